// Round 1
// baseline (2624.011 us; speedup 1.0000x reference)
//
#include <hip/hip_runtime.h>
#include <math.h>

#define BATCH    8192
#define TSTEPS   128
#define SDIM     16
#define HID      50
#define NGATE    200   // 4*HID
#define IN0      17    // SDIM + 1
#define FC1      25
#define BT       16    // batch tile per block
#define NTHREADS 256
#define HP       52    // padded row length for h/c (multiple of 4 for float4)

__device__ __forceinline__ float sigmoid_fast(float x) {
    return 1.0f / (1.0f + __expf(-x));
}

__device__ __forceinline__ float tanh_fast(float x) {
    // overflow-safe tanh via exp of negative argument
    float e = __expf(-2.0f * fabsf(x));
    float t = (1.0f - e) / (1.0f + e);
    return copysignf(t, x);
}

__global__ __launch_bounds__(NTHREADS, 2)
void lstm2_persistent_kernel(const float* __restrict__ feat,
                             const float* __restrict__ w_ih0,
                             const float* __restrict__ w_hh0,
                             const float* __restrict__ b_0,
                             const float* __restrict__ w_ih1,
                             const float* __restrict__ w_hh1,
                             const float* __restrict__ b_1,
                             const float* __restrict__ w_fc1,
                             const float* __restrict__ b_fc1,
                             const float* __restrict__ w_fc2,
                             const float* __restrict__ b_fc2,
                             float* __restrict__ out)
{
    __shared__ __align__(16) float sm_x[BT][20];     // 17 used (x[16] = prev_delta)
    __shared__ __align__(16) float sm_h0[BT][HP];
    __shared__ __align__(16) float sm_c0[BT][HP];
    __shared__ __align__(16) float sm_h1[BT][HP];
    __shared__ __align__(16) float sm_c1[BT][HP];
    __shared__ float sm_act[BT][NGATE];              // reused by both layers
    __shared__ float sm_r[BT][FC1 + 1];
    __shared__ __align__(16) float sm_wfc1[FC1][HP];
    __shared__ float sm_wfc2[FC1];
    __shared__ float sm_bfc1[FC1];
    __shared__ float sm_bfc2;

    const int tid = threadIdx.x;
    const int b0  = blockIdx.x * BT;

    // ---- preload per-gate weight rows into registers (threads >=200 load row 199 harmlessly)
    const int g = (tid < NGATE) ? tid : (NGATE - 1);
    const bool is_gate = (tid < NGATE);
    const bool is_tanh = ((tid / HID) == 2);   // gate order i,f,g,o -> rows [100,150) are tanh

    float wih0r[IN0], whh0r[HID], wih1r[HID], whh1r[HID];
    #pragma unroll
    for (int k = 0; k < IN0; ++k) wih0r[k] = w_ih0[g * IN0 + k];
    #pragma unroll
    for (int k = 0; k < HID; ++k) whh0r[k] = w_hh0[g * HID + k];
    #pragma unroll
    for (int k = 0; k < HID; ++k) wih1r[k] = w_ih1[g * HID + k];
    #pragma unroll
    for (int k = 0; k < HID; ++k) whh1r[k] = w_hh1[g * HID + k];
    const float bias0 = b_0[g];
    const float bias1 = b_1[g];

    // ---- init LDS state to zero, stage FC weights
    for (int i = tid; i < BT * HP; i += NTHREADS) {
        (&sm_h0[0][0])[i] = 0.0f;
        (&sm_c0[0][0])[i] = 0.0f;
        (&sm_h1[0][0])[i] = 0.0f;
        (&sm_c1[0][0])[i] = 0.0f;
    }
    for (int i = tid; i < BT * 20; i += NTHREADS) (&sm_x[0][0])[i] = 0.0f;
    for (int i = tid; i < FC1 * HP; i += NTHREADS) {
        int j = i / HP, k = i - j * HP;
        sm_wfc1[j][k] = (k < HID) ? w_fc1[j * HID + k] : 0.0f;
    }
    if (tid < FC1) { sm_wfc2[tid] = w_fc2[tid]; sm_bfc1[tid] = b_fc1[tid]; }
    if (tid == 0)  { sm_bfc2 = b_fc2[0]; }
    __syncthreads();

    for (int t = 0; t < TSTEPS; ++t) {
        // ---- phase 0: stage features for this step (one float per thread)
        {
            int b = tid >> 4, k = tid & 15;
            sm_x[b][k] = feat[(size_t)(b0 + b) * (TSTEPS * SDIM) + t * SDIM + k];
        }
        __syncthreads();

        // ---- phase 1: layer-0 gates (thread = gate row, loop over batch tile)
        if (is_gate) {
            for (int b = 0; b < BT; ++b) {
                const float4* xb = (const float4*)sm_x[b];
                float p0 = bias0, p1 = 0.f, p2 = 0.f, p3 = 0.f;
                #pragma unroll
                for (int q = 0; q < 4; ++q) {
                    float4 v = xb[q];
                    p0 += wih0r[4*q+0] * v.x; p1 += wih0r[4*q+1] * v.y;
                    p2 += wih0r[4*q+2] * v.z; p3 += wih0r[4*q+3] * v.w;
                }
                p0 += wih0r[16] * sm_x[b][16];
                const float4* hb = (const float4*)sm_h0[b];
                #pragma unroll
                for (int q = 0; q < 12; ++q) {
                    float4 v = hb[q];
                    p0 += whh0r[4*q+0] * v.x; p1 += whh0r[4*q+1] * v.y;
                    p2 += whh0r[4*q+2] * v.z; p3 += whh0r[4*q+3] * v.w;
                }
                p0 += whh0r[48] * sm_h0[b][48];
                p1 += whh0r[49] * sm_h0[b][49];
                float acc = (p0 + p1) + (p2 + p3);
                sm_act[b][tid] = is_tanh ? tanh_fast(acc) : sigmoid_fast(acc);
            }
        }
        __syncthreads();

        // ---- phase 2: layer-0 cell update
        for (int task = tid; task < BT * HID; task += NTHREADS) {
            int b = task / HID, j = task - b * HID;
            float i_ = sm_act[b][j];
            float f_ = sm_act[b][HID + j];
            float g_ = sm_act[b][2 * HID + j];
            float o_ = sm_act[b][3 * HID + j];
            float c  = f_ * sm_c0[b][j] + i_ * g_;
            sm_c0[b][j] = c;
            sm_h0[b][j] = o_ * tanh_fast(c);
        }
        __syncthreads();

        // ---- phase 3: layer-1 gates
        if (is_gate) {
            for (int b = 0; b < BT; ++b) {
                const float4* ha = (const float4*)sm_h0[b];
                const float4* hb = (const float4*)sm_h1[b];
                float p0 = bias1, p1 = 0.f, p2 = 0.f, p3 = 0.f;
                #pragma unroll
                for (int q = 0; q < 12; ++q) {
                    float4 v = ha[q];
                    p0 += wih1r[4*q+0] * v.x; p1 += wih1r[4*q+1] * v.y;
                    p2 += wih1r[4*q+2] * v.z; p3 += wih1r[4*q+3] * v.w;
                }
                p0 += wih1r[48] * sm_h0[b][48];
                p1 += wih1r[49] * sm_h0[b][49];
                #pragma unroll
                for (int q = 0; q < 12; ++q) {
                    float4 v = hb[q];
                    p0 += whh1r[4*q+0] * v.x; p1 += whh1r[4*q+1] * v.y;
                    p2 += whh1r[4*q+2] * v.z; p3 += whh1r[4*q+3] * v.w;
                }
                p0 += whh1r[48] * sm_h1[b][48];
                p1 += whh1r[49] * sm_h1[b][49];
                float acc = (p0 + p1) + (p2 + p3);
                sm_act[b][tid] = is_tanh ? tanh_fast(acc) : sigmoid_fast(acc);
            }
        }
        __syncthreads();

        // ---- phase 4: layer-1 cell update
        for (int task = tid; task < BT * HID; task += NTHREADS) {
            int b = task / HID, j = task - b * HID;
            float i_ = sm_act[b][j];
            float f_ = sm_act[b][HID + j];
            float g_ = sm_act[b][2 * HID + j];
            float o_ = sm_act[b][3 * HID + j];
            float c  = f_ * sm_c1[b][j] + i_ * g_;
            sm_c1[b][j] = c;
            sm_h1[b][j] = o_ * tanh_fast(c);
        }
        __syncthreads();

        // ---- phase 5a: fc1 + relu
        for (int task = tid; task < BT * FC1; task += NTHREADS) {
            int b = task / FC1, j = task - b * FC1;
            const float4* hb = (const float4*)sm_h1[b];
            const float4* wb = (const float4*)sm_wfc1[j];
            float p0 = sm_bfc1[j], p1 = 0.f, p2 = 0.f, p3 = 0.f;
            #pragma unroll
            for (int q = 0; q < 12; ++q) {
                float4 v = hb[q], w = wb[q];
                p0 += w.x * v.x; p1 += w.y * v.y; p2 += w.z * v.z; p3 += w.w * v.w;
            }
            p0 += sm_wfc1[j][48] * sm_h1[b][48];
            p1 += sm_wfc1[j][49] * sm_h1[b][49];
            float rr = (p0 + p1) + (p2 + p3);
            sm_r[b][j] = fmaxf(rr, 0.0f);
        }
        __syncthreads();

        // ---- phase 5b: fc2 -> delta, write out, feed back
        if (tid < BT) {
            float d = sm_bfc2;
            #pragma unroll
            for (int j = 0; j < FC1; ++j) d += sm_wfc2[j] * sm_r[tid][j];
            out[(size_t)(b0 + tid) * TSTEPS + t] = d;
            sm_x[tid][16] = d;   // prev_delta for next step
        }
        __syncthreads();
    }
}

extern "C" void kernel_launch(void* const* d_in, const int* in_sizes, int n_in,
                              void* d_out, int out_size, void* d_ws, size_t ws_size,
                              hipStream_t stream) {
    const float* feat  = (const float*)d_in[0];
    const float* w_ih0 = (const float*)d_in[1];
    const float* w_hh0 = (const float*)d_in[2];
    const float* b_0   = (const float*)d_in[3];
    const float* w_ih1 = (const float*)d_in[4];
    const float* w_hh1 = (const float*)d_in[5];
    const float* b_1   = (const float*)d_in[6];
    const float* w_fc1 = (const float*)d_in[7];
    const float* b_fc1 = (const float*)d_in[8];
    const float* w_fc2 = (const float*)d_in[9];
    const float* b_fc2 = (const float*)d_in[10];
    float* out = (float*)d_out;

    dim3 grid(BATCH / BT);
    dim3 block(NTHREADS);
    hipLaunchKernelGGL(lstm2_persistent_kernel, grid, block, 0, stream,
                       feat, w_ih0, w_hh0, b_0, w_ih1, w_hh1, b_1,
                       w_fc1, b_fc1, w_fc2, b_fc2, out);
}